// Round 7
// baseline (79.513 us; speedup 1.0000x reference)
//
#include <hip/hip_runtime.h>
#include <hip/hip_fp16.h>

#define LATENT 128
#define DQK    32
#define BB     4
#define NN     16384
#define KK     64
#define TOTAL_EDGES (BB * NN * KK)   // 4,194,304
#define TOTAL_NODES (BB * NN)        // 65,536
#define EPB     (NN * KK)            // edges per batch = 2^20
#define PADF   132                   // f32 LDS row stride (floats)
#define PADH   136                   // f16 LDS row stride (halves)
#define EG     8                     // 16-edge groups per wave
#define EDGE_BLOCKS 2048             // per batch: 2^20 edges / 512
#define PROJ_BLOCKS 256              // per batch: 16384 nodes / 64

typedef _Float16 half8 __attribute__((ext_vector_type(8)));
typedef float    f32x4 __attribute__((ext_vector_type(4)));

// ---------------------------------------------------------------------------
// Fused stage kernel. Block role by blockIdx: first nProj blocks run the
// projection for batch pb; the rest run edge-dots for batch eb (whose proj
// completed in the PREVIOUS stage -> stream order guarantees visibility).
// Static LDS (51.5 KB) is reserved by all blocks: 3 blocks/CU, edge gets
// 12 waves/CU which still saturates the per-CU address pipe (r4-r6 evidence).
// ---------------------------------------------------------------------------
__global__ __launch_bounds__(256, 2) void stage_kernel(
    const float* __restrict__ features,  // [B*N, 128]
    const float* __restrict__ Wk,        // [32, 128]
    const float* __restrict__ bk,        // [32]
    const float* __restrict__ Wq,        // [32, 128]
    const float* __restrict__ bq,        // [32]
    const int* __restrict__ xidx,        // indices row 1, [B*N*K]
    const int* __restrict__ yidx,        // indices row 2
    __half* __restrict__ ks,             // [B*N, 32] f16
    __half* __restrict__ qs,
    float* __restrict__ out,             // [B*N*K]
    int eb, int pb, int nProj)
{
    __shared__ float  sf[64 * PADF];     // feature tile (f32)   33.8 KB
    __shared__ __half swh[64 * PADH];    // Wk|Wq tile   (f16)   17.4 KB
    __shared__ float  sb[64];

    const int t = threadIdx.x;

    if ((int)blockIdx.x < nProj) {
        // ------------------- projection role: batch pb -------------------
        const int node0 = (pb << 14) + blockIdx.x * 64;

        // Stage W rows 0..31=Wk, 32..63=Wq as f16
        #pragma unroll
        for (int j = 0; j < 8; ++j) {
            int idx = t + j * 256;
            int r = idx >> 5;
            int c = idx & 31;
            const float4* src = (r < 32) ? (const float4*)Wk : (const float4*)Wq;
            float4 v = src[(size_t)(r & 31) * 32 + c];
            *(__half2*)&swh[r * PADH + c * 4]     = __floats2half2_rn(v.x, v.y);
            *(__half2*)&swh[r * PADH + c * 4 + 2] = __floats2half2_rn(v.z, v.w);
        }
        if (t < 64) sb[t] = (t < 32) ? bk[t] : bq[t - 32];

        // Stage feature tile (64 rows, coalesced float4)
        #pragma unroll
        for (int j = 0; j < 8; ++j) {
            int idx = t + j * 256;
            int r = idx >> 5;
            int c = idx & 31;
            float4 v = ((const float4*)(features + (size_t)(node0 + r) * LATENT))[c];
            *(float4*)&sf[r * PADF + c * 4] = v;
        }
        __syncthreads();

        const int tx = t & 15;           // dim group: dims tx + 16u
        const int ty = t >> 4;           // node group: nodes 4*ty + i

        float acc[4][4];
        #pragma unroll
        for (int i = 0; i < 4; ++i)
            #pragma unroll
            for (int u = 0; u < 4; ++u) acc[i][u] = 0.f;

        #pragma unroll 4
        for (int kk = 0; kk < 32; ++kk) {
            float4 a[4];
            #pragma unroll
            for (int i = 0; i < 4; ++i)
                a[i] = *(const float4*)&sf[(ty * 4 + i) * PADF + kk * 4];
            float4 b[4];
            #pragma unroll
            for (int u = 0; u < 4; ++u) {
                const int row = tx + 16 * u;
                float2 f01 = __half22float2(*(const __half2*)&swh[row * PADH + kk * 4]);
                float2 f23 = __half22float2(*(const __half2*)&swh[row * PADH + kk * 4 + 2]);
                b[u] = make_float4(f01.x, f01.y, f23.x, f23.y);
            }
            #pragma unroll
            for (int i = 0; i < 4; ++i)
                #pragma unroll
                for (int u = 0; u < 4; ++u)
                    acc[i][u] += a[i].x * b[u].x + a[i].y * b[u].y
                               + a[i].z * b[u].z + a[i].w * b[u].w;
        }

        #pragma unroll
        for (int u = 0; u < 4; ++u) {
            const int d = tx + 16 * u;
            const float bias = sb[d];
            __half* base = (d < 32) ? ks : qs;
            const int dd = d & 31;
            #pragma unroll
            for (int i = 0; i < 4; ++i) {
                const int node = node0 + ty * 4 + i;
                base[(size_t)node * DQK + dd] = __float2half(acc[i][u] + bias);
            }
        }
    } else {
        // --------------------- edge role: batch eb -----------------------
        const int ebid = blockIdx.x - nProj;
        const int lane = t & 63;
        const int wave = (ebid * 256 + t) >> 6;        // 0..8191 within batch
        const int i = lane & 15;                        // edge within group
        const int c = lane >> 4;                        // k-chunk (8 f16)
        const int e_base = (eb << 20) + wave * (16 * EG);
        const int nodebase = eb << 14;                  // eb * NN

        const _Float16* ksh = (const _Float16*)ks;
        const _Float16* qsh = (const _Float16*)qs;

        int xs[EG], ys[EG];
        #pragma unroll
        for (int g = 0; g < EG; ++g) {
            xs[g] = xidx[e_base + g * 16 + i];
            ys[g] = yidx[e_base + g * 16 + i];
        }
        __builtin_amdgcn_sched_barrier(0);

        half8 kv[EG], qv[EG];
        #pragma unroll
        for (int g = 0; g < EG; ++g) {
            kv[g] = *(const half8*)(ksh + (((size_t)(nodebase + xs[g])) << 5) + (c << 3));
            qv[g] = *(const half8*)(qsh + (((size_t)(nodebase + ys[g])) << 5) + (c << 3));
        }
        __builtin_amdgcn_sched_barrier(0);

        // MFMA: gather layout == A/B fragment of mfma_f32_16x16x32_f16.
        // Wanted dots = diagonal C[i][i] (transpose-robust);
        // C[i][i] at lane ((i>>2)<<4)|i, reg i&3.
        const bool writer = (c == (i >> 2));
        const int reg = i & 3;
        #pragma unroll
        for (int g = 0; g < EG; ++g) {
            f32x4 acc = {0.f, 0.f, 0.f, 0.f};
            acc = __builtin_amdgcn_mfma_f32_16x16x32_f16(kv[g], qv[g], acc, 0, 0, 0);
            float v = acc[0];
            v = (reg == 1) ? acc[1] : v;
            v = (reg == 2) ? acc[2] : v;
            v = (reg == 3) ? acc[3] : v;
            if (writer) out[e_base + g * 16 + i] = v * 0.17677669529663687f;
        }
    }
}

// ---------------------------------------------------------------------------
extern "C" void kernel_launch(void* const* d_in, const int* in_sizes, int n_in,
                              void* d_out, int out_size, void* d_ws, size_t ws_size,
                              hipStream_t stream) {
    // Input order: indices, img, features, Wk, bk, Wq, bq
    const int*   indices  = (const int*)d_in[0];
    const float* features = (const float*)d_in[2];
    const float* Wk       = (const float*)d_in[3];
    const float* bk       = (const float*)d_in[4];
    const float* Wq       = (const float*)d_in[5];
    const float* bq       = (const float*)d_in[6];
    float* out = (float*)d_out;

    __half* ks = (__half*)d_ws;                           // [B*N, 32] f16
    __half* qs = ks + (size_t)TOTAL_NODES * DQK;

    const int* xidx = indices + (size_t)1 * TOTAL_EDGES;  // row 1 -> keys
    const int* yidx = indices + (size_t)2 * TOTAL_EDGES;  // row 2 -> queries

    // Batch pipeline: proj(0); edge(b)||proj(b+1) for b=0..2; edge(3).
    for (int s = 0; s < 5; ++s) {
        const int eb = s - 1;                       // edge batch this stage
        const int pb = s;                           // proj batch this stage
        const int nProj = (pb < BB) ? PROJ_BLOCKS : 0;
        const int nEdge = (eb >= 0) ? EDGE_BLOCKS : 0;
        stage_kernel<<<nProj + nEdge, 256, 0, stream>>>(
            features, Wk, bk, Wq, bq, xidx, yidx, ks, qs, out, eb, pb, nProj);
    }
}

// Round 8
// 74.047 us; speedup vs baseline: 1.0738x; 1.0738x over previous
//
#include <hip/hip_runtime.h>
#include <hip/hip_fp16.h>

#define LATENT 128
#define DQK    32
#define BB     4
#define NN     16384
#define KK     64
#define TOTAL_EDGES (BB * NN * KK)   // 4,194,304
#define TOTAL_NODES (BB * NN)        // 65,536
#define PADF   132                   // f32 LDS row stride (floats)
#define EPT    4                     // edges per thread (edge kernel)

// ---------------------------------------------------------------------------
// i8 dot helper: 4 x i8 pairs -> i32 accumulate
// ---------------------------------------------------------------------------
__device__ __forceinline__ int dot4i8(int a, int b, int c) {
#if __has_builtin(__builtin_amdgcn_sdot4)
    return __builtin_amdgcn_sdot4(a, b, c, false);
#else
    c += ((a << 24) >> 24) * ((b << 24) >> 24);
    c += ((a << 16) >> 24) * ((b << 16) >> 24);
    c += ((a <<  8) >> 24) * ((b <<  8) >> 24);
    c += (a >> 24) * (b >> 24);
    return c;
#endif
}

// ---------------------------------------------------------------------------
// Kernel 1: proj + int8 row quantization.
// r4 core (LDS-tiled, 4x4 micro-tile, ~12us) + epilogue:
//   rowmax over 32 dims via shfl_xor across the 16 tx-lanes,
//   iq = rint(val * 127/rowmax), byte-stores (16 consecutive bytes/node),
//   per-row scale = rowmax/127 stored f16.
// ---------------------------------------------------------------------------
__global__ __launch_bounds__(256, 2) void proj_kernel(
    const float* __restrict__ features,  // [B*N, 128]
    const float* __restrict__ Wk,        // [32, 128]
    const float* __restrict__ bk,        // [32]
    const float* __restrict__ Wq,        // [32, 128]
    const float* __restrict__ bq,        // [32]
    signed char* __restrict__ ks8,       // [B*N, 32] i8
    signed char* __restrict__ qs8,       // [B*N, 32] i8
    __half* __restrict__ sk,             // [B*N] f16 row scales
    __half* __restrict__ sq)
{
    __shared__ float sf[64 * PADF];
    __shared__ float sw[64 * PADF];      // rows 0..31 = Wk, 32..63 = Wq
    __shared__ float sb[64];

    const int t = threadIdx.x;
    const int node0 = blockIdx.x * 64;

    #pragma unroll
    for (int j = 0; j < 8; ++j) {
        int idx = t + j * 256;
        int r = idx >> 5;
        int c = idx & 31;
        const float4* src = (r < 32) ? (const float4*)Wk : (const float4*)Wq;
        float4 v = src[(size_t)(r & 31) * 32 + c];
        *(float4*)&sw[r * PADF + c * 4] = v;
    }
    if (t < 64) sb[t] = (t < 32) ? bk[t] : bq[t - 32];

    #pragma unroll
    for (int j = 0; j < 8; ++j) {
        int idx = t + j * 256;
        int r = idx >> 5;
        int c = idx & 31;
        float4 v = ((const float4*)(features + (size_t)(node0 + r) * LATENT))[c];
        *(float4*)&sf[r * PADF + c * 4] = v;
    }
    __syncthreads();

    const int tx = t & 15;               // dims tx + 16u
    const int ty = t >> 4;               // nodes ty*4 + i

    float acc[4][4];
    #pragma unroll
    for (int i = 0; i < 4; ++i)
        #pragma unroll
        for (int u = 0; u < 4; ++u) acc[i][u] = 0.f;

    #pragma unroll 4
    for (int kk = 0; kk < 32; ++kk) {
        float4 a[4], b[4];
        #pragma unroll
        for (int i = 0; i < 4; ++i)
            a[i] = *(const float4*)&sf[(ty * 4 + i) * PADF + kk * 4];
        #pragma unroll
        for (int u = 0; u < 4; ++u)
            b[u] = *(const float4*)&sw[(tx + 16 * u) * PADF + kk * 4];
        #pragma unroll
        for (int i = 0; i < 4; ++i)
            #pragma unroll
            for (int u = 0; u < 4; ++u)
                acc[i][u] += a[i].x * b[u].x + a[i].y * b[u].y
                           + a[i].z * b[u].z + a[i].w * b[u].w;
    }

    // ---- quantizing epilogue ----
    // u=0: ks dim tx ; u=1: ks dim tx+16 ; u=2: qs dim tx ; u=3: qs dim tx+16
    float vk0[4], vk1[4], vq0[4], vq1[4], mk[4], mq[4];
    #pragma unroll
    for (int i = 0; i < 4; ++i) {
        vk0[i] = acc[i][0] + sb[tx];
        vk1[i] = acc[i][1] + sb[tx + 16];
        vq0[i] = acc[i][2] + sb[tx + 32];
        vq1[i] = acc[i][3] + sb[tx + 48];
        mk[i] = fmaxf(fabsf(vk0[i]), fabsf(vk1[i]));
        mq[i] = fmaxf(fabsf(vq0[i]), fabsf(vq1[i]));
    }
    #pragma unroll
    for (int mask = 1; mask < 16; mask <<= 1) {
        #pragma unroll
        for (int i = 0; i < 4; ++i) {
            mk[i] = fmaxf(mk[i], __shfl_xor(mk[i], mask));
            mq[i] = fmaxf(mq[i], __shfl_xor(mq[i], mask));
        }
    }
    #pragma unroll
    for (int i = 0; i < 4; ++i) {
        const int node = node0 + ty * 4 + i;
        const float invk = (mk[i] > 0.f) ? 127.f / mk[i] : 0.f;
        const float invq = (mq[i] > 0.f) ? 127.f / mq[i] : 0.f;
        signed char* kr = ks8 + (size_t)node * 32;
        signed char* qr = qs8 + (size_t)node * 32;
        kr[tx]      = (signed char)__float2int_rn(vk0[i] * invk);
        kr[tx + 16] = (signed char)__float2int_rn(vk1[i] * invk);
        qr[tx]      = (signed char)__float2int_rn(vq0[i] * invq);
        qr[tx + 16] = (signed char)__float2int_rn(vq1[i] * invq);
        if (tx == 0) {
            sk[node] = __float2half(mk[i] * (1.f / 127.f));
            sq[node] = __float2half(mq[i] * (1.f / 127.f));
        }
    }
}

// ---------------------------------------------------------------------------
// Kernel 2: i8 edge dots. 1 lane = 1 edge, EPT edges/thread pipelined.
// Per edge only 4 divergent 16B lane-addresses (kv 2 + qv 2) vs 8 for f16
// -> divergent-address floor halves (54.6 -> 27.3 us).
// Scales come from LDS (64KB: both 16K-entry f16 tables) -> DS pipe, not TA.
// dot is lane-local via v_dot4_i32_i8; indices/outputs coalesced.
// ---------------------------------------------------------------------------
__global__ __launch_bounds__(512, 2) void edge_kernel(
    const int* __restrict__ xidx,        // indices row 1, [B*N*K]
    const int* __restrict__ yidx,        // indices row 2
    const signed char* __restrict__ ks8, // [B*N, 32] i8
    const signed char* __restrict__ qs8,
    const __half* __restrict__ sk,       // [B*N] f16
    const __half* __restrict__ sq,
    float* __restrict__ out)             // [B*N*K]
{
    __shared__ __half ssk[NN];           // 32 KB
    __shared__ __half ssq[NN];           // 32 KB

    const int t = threadIdx.x;
    const int b = blockIdx.x >> 9;       // 512 blocks per batch

    // Stage scale tables (coalesced uint4: 2048 per table, 4/thread each)
    const uint4* gk = (const uint4*)(sk + (size_t)b * NN);
    const uint4* gq = (const uint4*)(sq + (size_t)b * NN);
    uint4* lk = (uint4*)ssk;
    uint4* lq = (uint4*)ssq;
    #pragma unroll
    for (int j = 0; j < 4; ++j) {
        lk[t + j * 512] = gk[t + j * 512];
        lq[t + j * 512] = gq[t + j * 512];
    }
    __syncthreads();

    const int base_e = (blockIdx.x & 511) * (512 * EPT);  // within batch
    const int gbase  = b << 20;                            // batch edge offset
    const size_t nodebase = (size_t)b << 14;               // b * NN

    // Phase 1: coalesced index loads
    int xs[EPT], ys[EPT];
    #pragma unroll
    for (int m = 0; m < EPT; ++m) {
        const int e = base_e + m * 512 + t;
        xs[m] = xidx[gbase + e];
        ys[m] = yidx[gbase + e];
    }
    __builtin_amdgcn_sched_barrier(0);

    // Phase 2: all divergent gathers in flight (4 per edge, 16 total)
    uint4 kv0[EPT], kv1[EPT], qv0[EPT], qv1[EPT];
    const uint4* k4 = (const uint4*)ks8;
    const uint4* q4 = (const uint4*)qs8;
    #pragma unroll
    for (int m = 0; m < EPT; ++m) {
        const size_t xo = (nodebase + (size_t)xs[m]) << 1;  // uint4 units
        const size_t yo = (nodebase + (size_t)ys[m]) << 1;
        kv0[m] = k4[xo];
        kv1[m] = k4[xo + 1];
        qv0[m] = q4[yo];
        qv1[m] = q4[yo + 1];
    }
    __builtin_amdgcn_sched_barrier(0);

    // Phase 3: lane-local i8 dot + LDS scale lookup + coalesced store
    #pragma unroll
    for (int m = 0; m < EPT; ++m) {
        int d = 0;
        d = dot4i8((int)kv0[m].x, (int)qv0[m].x, d);
        d = dot4i8((int)kv0[m].y, (int)qv0[m].y, d);
        d = dot4i8((int)kv0[m].z, (int)qv0[m].z, d);
        d = dot4i8((int)kv0[m].w, (int)qv0[m].w, d);
        d = dot4i8((int)kv1[m].x, (int)qv1[m].x, d);
        d = dot4i8((int)kv1[m].y, (int)qv1[m].y, d);
        d = dot4i8((int)kv1[m].z, (int)qv1[m].z, d);
        d = dot4i8((int)kv1[m].w, (int)qv1[m].w, d);
        const float skx = __half2float(ssk[xs[m]]);
        const float sqy = __half2float(ssq[ys[m]]);
        const int e = base_e + m * 512 + t;
        out[gbase + e] = (float)d * skx * sqy * 0.17677669529663687f;
    }
}

// ---------------------------------------------------------------------------
extern "C" void kernel_launch(void* const* d_in, const int* in_sizes, int n_in,
                              void* d_out, int out_size, void* d_ws, size_t ws_size,
                              hipStream_t stream) {
    // Input order: indices, img, features, Wk, bk, Wq, bq
    const int*   indices  = (const int*)d_in[0];
    const float* features = (const float*)d_in[2];
    const float* Wk       = (const float*)d_in[3];
    const float* bk       = (const float*)d_in[4];
    const float* Wq       = (const float*)d_in[5];
    const float* bq       = (const float*)d_in[6];
    float* out = (float*)d_out;

    // ws layout: ks8 (2MB) | qs8 (2MB) | sk (128KB f16) | sq (128KB f16)
    signed char* ks8 = (signed char*)d_ws;
    signed char* qs8 = ks8 + (size_t)TOTAL_NODES * 32;
    __half* sk = (__half*)(qs8 + (size_t)TOTAL_NODES * 32);
    __half* sq = sk + TOTAL_NODES;

    const int* xidx = indices + (size_t)1 * TOTAL_EDGES;  // row 1 -> keys
    const int* yidx = indices + (size_t)2 * TOTAL_EDGES;  // row 2 -> queries

    proj_kernel<<<TOTAL_NODES / 64, 256, 0, stream>>>(
        features, Wk, bk, Wq, bq, ks8, qs8, sk, sq);
    // 512 blocks/batch x 4 batches; 512 threads x EPT(4) edges = 2048 edges/block
    edge_kernel<<<BB * 512, 512, 0, stream>>>(xidx, yidx, ks8, qs8, sk, sq, out);
}